// Round 9
// baseline (409.112 us; speedup 1.0000x reference)
//
#include <hip/hip_runtime.h>

// ---------------------------------------------------------------------------
// 3-layer GCN forward. out[d] = relu( dinv[d]*( sum_{s->d} g[s] + g[d] ) + b ),
// g = (x@W)*dinv stored bf16 in 16-FEATURE SLICES [slice][N][16] (3.2MB per
// slice < 4MB per-XCD L2); aggregation runs one dispatch per slice so the
// slice table stays L2-resident (r7: 160MB misses @2.4TB/s was the cap).
// Layer GEMMs: split-bf16 MFMA (x = hi+lo, 3 passes => ~f32 accuracy).
// r8 fusion reverted (matvec epilogue made agg VALU-bound, +50us).
// CSR built per call via two-level counting sort (bucket = dst>>9), packed u32.
// ---------------------------------------------------------------------------

#define BSH 9                 // 512 nodes per bucket
#define BNODES (1 << BSH)

typedef __attribute__((ext_vector_type(8))) short bf16x8;
typedef __attribute__((ext_vector_type(4))) float f32x4;

__device__ inline ushort f2bf(float x) {   // round-to-nearest-even f32->bf16
    uint u = __float_as_uint(x);
    return (ushort)((u + 0x7fffu + ((u >> 16) & 1u)) >> 16);
}
__device__ inline float bf2f(ushort h) { return __uint_as_float(((uint)h) << 16); }
__device__ inline void split2(float x, ushort& h, ushort& l) {
    ushort hh = f2bf(x);
    h = hh;
    l = f2bf(x - bf2f(hh));
}

// fused: bucket histogram of dst (blocks < HB) + W1/W2/W3 split/transpose
__global__ __launch_bounds__(256) void k_pre(
    const int* __restrict__ dst, int* __restrict__ bcnt, int E, int HB,
    const float* __restrict__ W1, const float* __restrict__ W2,
    const float* __restrict__ W3,
    ushort* __restrict__ Wh1, ushort* __restrict__ Wl1,
    ushort* __restrict__ Wh2, ushort* __restrict__ Wl2,
    ushort* __restrict__ Wh3, ushort* __restrict__ Wl3)
{
    if ((int)blockIdx.x < HB) {
        __shared__ int h[256];
        int t = threadIdx.x;
        h[t] = 0;
        __syncthreads();
        for (int i = blockIdx.x * 256 + t; i < E; i += HB * 256)
            atomicAdd(&h[dst[i] >> BSH], 1);
        __syncthreads();
        if (h[t]) atomicAdd(&bcnt[t], h[t]);
        return;
    }
    int i = (blockIdx.x - HB) * 256 + threadIdx.x;
    ushort h, l;
    if (i < 16384) {                       // W1: 256x64
        int k = i >> 6, n = i & 63;
        split2(W1[i], h, l);
        Wh1[n * 256 + k] = h; Wl1[n * 256 + k] = l;
    } else if (i < 16384 + 2048) {         // W2: 64x32
        int j = i - 16384;
        int k = j >> 5, n = j & 31;
        split2(W2[j], h, l);
        Wh2[n * 64 + k] = h; Wl2[n * 64 + k] = l;
    } else if (i < 16384 + 2048 + 512) {   // W3: 32x16
        int j = i - 18432;
        int k = j >> 4, n = j & 15;
        split2(W3[j], h, l);
        Wh3[n * 32 + k] = h; Wl3[n * 32 + k] = l;
    }
}

// scan bucket counts -> boff (exclusive), init bcur. NB <= 1024.
__global__ __launch_bounds__(1024) void k_bscan(const int* __restrict__ bcnt,
                                                int* __restrict__ boff,
                                                int* __restrict__ bcur, int NB) {
    __shared__ int s[1024];
    int t = threadIdx.x;
    int v = (t < NB) ? bcnt[t] : 0;
    s[t] = v;
    __syncthreads();
    for (int off = 1; off < 1024; off <<= 1) {
        int a = (t >= off) ? s[t - off] : 0;
        __syncthreads();
        s[t] += a;
        __syncthreads();
    }
    if (t < NB) {
        int ex = s[t] - v;
        boff[t] = ex;
        bcur[t] = ex;
    }
    if (t == NB - 1) boff[NB] = s[t];
}

// partition edges into bucket-contiguous packed (local_dst<<23 | src) words
template <int CH>
__global__ __launch_bounds__(256) void k_part(const int* __restrict__ src,
                                              const int* __restrict__ dst,
                                              int* __restrict__ bcur,
                                              uint* __restrict__ pairs,
                                              int E, int NB) {
    __shared__ int lh[256];
    __shared__ int lbase[256];
    const int t = threadIdx.x;
    const int e0 = blockIdx.x * CH;
    const int n = min(CH, E - e0);

    lh[t] = 0;
    __syncthreads();
    for (int i = t; i < n; i += 256) atomicAdd(&lh[dst[e0 + i] >> BSH], 1);
    __syncthreads();
    if (t < NB && lh[t] > 0) lbase[t] = atomicAdd(&bcur[t], lh[t]);
    __syncthreads();
    lh[t] = 0;
    __syncthreads();
    for (int i = t; i < n; i += 256) {
        int d = dst[e0 + i];
        int b = d >> BSH;
        int r = atomicAdd(&lh[b], 1);
        pairs[(long)lbase[b] + r] = ((uint)(d & (BNODES - 1)) << 23) | (uint)src[e0 + i];
    }
}

// per-bucket: per-node histogram + scan (LDS), emit row_off/dinv, scatter esrc
__global__ __launch_bounds__(1024) void k_bucket(const uint* __restrict__ pairs,
                                                 const int* __restrict__ boff,
                                                 int* __restrict__ row_off,
                                                 float* __restrict__ dinv,
                                                 int* __restrict__ esrc,
                                                 int N, int NB, int E) {
    __shared__ int cnt[BNODES];
    __shared__ int sc[BNODES];
    __shared__ int cur[BNODES];
    const int b = blockIdx.x;
    const int t = threadIdx.x;
    const int base = b << BSH;
    const int nn = min(BNODES, N - base);
    const int ebase = boff[b], eend = boff[b + 1];

    if (t < BNODES) cnt[t] = 0;
    __syncthreads();
    for (int e = ebase + t; e < eend; e += 1024)
        atomicAdd(&cnt[pairs[e] >> 23], 1);
    __syncthreads();
    if (t < BNODES) sc[t] = cnt[t];
    __syncthreads();
    for (int off = 1; off < BNODES; off <<= 1) {
        int a = (t < BNODES && t >= off) ? sc[t - off] : 0;
        __syncthreads();
        if (t < BNODES) sc[t] += a;
        __syncthreads();
    }
    if (t < nn) {
        int ex = sc[t] - cnt[t];
        row_off[base + t] = ebase + ex;
        cur[t] = ex;
        dinv[base + t] = rsqrtf((float)(cnt[t] + 1));
    }
    if (b == NB - 1 && t == 0) row_off[N] = E;
    __syncthreads();
    for (int e = ebase + t; e < eend; e += 1024) {
        uint p = pairs[e];
        int r = atomicAdd(&cur[p >> 23], 1);
        esrc[ebase + r] = (int)(p & 0x7fffffu);
    }
}

// ---------------------------------------------------------------------------
// Split-bf16 MFMA GEMM: writes G in slice layout [NT][N][16] bf16.
// Block = 64 rows x OF cols, 4 waves (16 rows each), BK=32 per step.
// ---------------------------------------------------------------------------
template <int K, int OF>
__global__ __launch_bounds__(256) void k_mfma(
    const float* __restrict__ X, int sx,
    const int* __restrict__ nodes,          // may be null (identity)
    const ushort* __restrict__ Wh,          // [OF][K] bf16
    const ushort* __restrict__ Wl,
    const float* __restrict__ dinv,
    ushort* __restrict__ G,                 // bf16 slices [OF/16][N][16]
    int N)
{
    constexpr int BM = 64, BK = 32, LDF = 40;
    constexpr int NT = OF / 16;             // MFMA col tiles = slices
    __shared__ ushort Ah[BM * LDF], Al[BM * LDF];
    __shared__ ushort Bh[OF * LDF], Bl[OF * LDF];

    const int tid = threadIdx.x;
    const int l = tid & 63;
    const int w = tid >> 6;                 // wave id: rows w*16..w*16+15
    const int m0 = blockIdx.x * BM;
    const int lm = l & 15, kg = l >> 4;

    f32x4 acc[NT];
#pragma unroll
    for (int nt = 0; nt < NT; ++nt) acc[nt] = (f32x4){0.f, 0.f, 0.f, 0.f};

    for (int k0 = 0; k0 < K; k0 += BK) {
        __syncthreads();
#pragma unroll
        for (int t = 0; t < 2; ++t) {
            int i = tid + t * 256;
            int m = i >> 3, kq = i & 7;
            float4 v = make_float4(0.f, 0.f, 0.f, 0.f);
            if (m0 + m < N) {
                long row = nodes ? (long)nodes[m0 + m] : (long)(m0 + m);
                v = *reinterpret_cast<const float4*>(X + row * (long)sx + k0 + kq * 4);
            }
            ushort4 hh, ll;
            split2(v.x, hh.x, ll.x); split2(v.y, hh.y, ll.y);
            split2(v.z, hh.z, ll.z); split2(v.w, hh.w, ll.w);
            *reinterpret_cast<ushort4*>(&Ah[m * LDF + kq * 4]) = hh;
            *reinterpret_cast<ushort4*>(&Al[m * LDF + kq * 4]) = ll;
        }
        for (int i = tid; i < OF * 16; i += 256) {
            int n = i >> 4, ku = i & 15;
            *reinterpret_cast<uint*>(&Bh[n * LDF + ku * 2]) =
                *reinterpret_cast<const uint*>(Wh + (long)n * K + k0 + ku * 2);
            *reinterpret_cast<uint*>(&Bl[n * LDF + ku * 2]) =
                *reinterpret_cast<const uint*>(Wl + (long)n * K + k0 + ku * 2);
        }
        __syncthreads();

        bf16x8 ah = *reinterpret_cast<bf16x8*>(&Ah[(w * 16 + lm) * LDF + kg * 8]);
        bf16x8 al = *reinterpret_cast<bf16x8*>(&Al[(w * 16 + lm) * LDF + kg * 8]);
#pragma unroll
        for (int nt = 0; nt < NT; ++nt) {
            bf16x8 bh = *reinterpret_cast<bf16x8*>(&Bh[(nt * 16 + lm) * LDF + kg * 8]);
            bf16x8 bl = *reinterpret_cast<bf16x8*>(&Bl[(nt * 16 + lm) * LDF + kg * 8]);
            acc[nt] = __builtin_amdgcn_mfma_f32_16x16x32_bf16(al, bh, acc[nt], 0, 0, 0);
            acc[nt] = __builtin_amdgcn_mfma_f32_16x16x32_bf16(ah, bl, acc[nt], 0, 0, 0);
            acc[nt] = __builtin_amdgcn_mfma_f32_16x16x32_bf16(ah, bh, acc[nt], 0, 0, 0);
        }
    }
#pragma unroll
    for (int r = 0; r < 4; ++r) {
        int m = m0 + w * 16 + kg * 4 + r;
        if (m < N) {
            float dv = dinv[m];
#pragma unroll
            for (int nt = 0; nt < NT; ++nt)
                G[(long)nt * N * 16 + (long)m * 16 + lm] = f2bf(acc[nt][r] * dv);
        }
    }
}

// ---------------------------------------------------------------------------
// Per-slice CSR aggregation (bf16 gather from 3.2MB L2-resident slice table)
// + self-loop + dinv/bias/relu epilogue. One wave per node; 4 lanes per edge
// (uint2 = 4 bf16), 16 edges in parallel, 32 in flight (2-deep).
// Launched once per 16-feature slice; bias/y pre-offset to slice start.
// ---------------------------------------------------------------------------
template <int OSTRIDE>
__global__ __launch_bounds__(256) void k_aggs(
    const int* __restrict__ row_off, const int* __restrict__ esrc,
    const uint2* __restrict__ gs,    // slice table [N][4] uint2
    const float* __restrict__ dinv,
    const float* __restrict__ bias,  // 16 floats (slice)
    float* __restrict__ y,           // stride OSTRIDE, pre-offset to slice
    int N)
{
    const int lane = threadIdx.x & 63;
    const int q = lane & 3;          // feature quad within slice
    const int sub = lane >> 2;       // edge sub-slot 0..15
    const int n = blockIdx.x * 4 + (threadIdx.x >> 6);
    if (n >= N) return;
    const int start = row_off[n], end = row_off[n + 1];

    float a0[4] = {0.f, 0.f, 0.f, 0.f};
    float a1[4] = {0.f, 0.f, 0.f, 0.f};
    int e = start + sub;
    for (; e + 16 < end; e += 32) {
        int s0 = esrc[e];
        int s1 = esrc[e + 16];
        uint2 w0 = gs[(long)s0 * 4 + q];
        uint2 w1 = gs[(long)s1 * 4 + q];
        a0[0] += __uint_as_float(w0.x << 16);
        a0[1] += __uint_as_float(w0.x & 0xffff0000u);
        a0[2] += __uint_as_float(w0.y << 16);
        a0[3] += __uint_as_float(w0.y & 0xffff0000u);
        a1[0] += __uint_as_float(w1.x << 16);
        a1[1] += __uint_as_float(w1.x & 0xffff0000u);
        a1[2] += __uint_as_float(w1.y << 16);
        a1[3] += __uint_as_float(w1.y & 0xffff0000u);
    }
    for (; e < end; e += 16) {
        uint2 w = gs[(long)esrc[e] * 4 + q];
        a0[0] += __uint_as_float(w.x << 16);
        a0[1] += __uint_as_float(w.x & 0xffff0000u);
        a0[2] += __uint_as_float(w.y << 16);
        a0[3] += __uint_as_float(w.y & 0xffff0000u);
    }
    float t[4];
#pragma unroll
    for (int j = 0; j < 4; ++j) t[j] = a0[j] + a1[j];
#pragma unroll
    for (int m = 4; m < 64; m <<= 1)
#pragma unroll
        for (int j = 0; j < 4; ++j) t[j] += __shfl_xor(t[j], m, 64);

    if (sub == 0) {
        uint2 sv = gs[(long)n * 4 + q];   // self loop
        t[0] += __uint_as_float(sv.x << 16);
        t[1] += __uint_as_float(sv.x & 0xffff0000u);
        t[2] += __uint_as_float(sv.y << 16);
        t[3] += __uint_as_float(sv.y & 0xffff0000u);
        float dv = dinv[n];
        float4 bb = *reinterpret_cast<const float4*>(bias + q * 4);
        float4 o;
        o.x = fmaxf(fmaf(t[0], dv, bb.x), 0.f);
        o.y = fmaxf(fmaf(t[1], dv, bb.y), 0.f);
        o.z = fmaxf(fmaf(t[2], dv, bb.z), 0.f);
        o.w = fmaxf(fmaf(t[3], dv, bb.w), 0.f);
        *reinterpret_cast<float4*>(&y[(long)n * OSTRIDE + q * 4]) = o;
    }
}

extern "C" void kernel_launch(void* const* d_in, const int* in_sizes, int n_in,
                              void* d_out, int out_size, void* d_ws, size_t ws_size,
                              hipStream_t stream) {
    const int*   nodes = (const int*)d_in[0];
    const int*   edges = (const int*)d_in[1];
    const float* emb   = (const float*)d_in[2];
    const float* W1    = (const float*)d_in[3];
    const float* b1    = (const float*)d_in[4];
    const float* W2    = (const float*)d_in[5];
    const float* b2    = (const float*)d_in[6];
    const float* W3    = (const float*)d_in[7];
    const float* b3    = (const float*)d_in[8];

    const int N = in_sizes[0];
    const int E = in_sizes[1] / 2;
    const int* src  = edges;
    const int* dstv = edges + E;
    const int NB = (N + BNODES - 1) >> BSH;   // 196 for N=100000

    char* ws = (char*)d_ws;
    size_t off = 0;
    auto alloc = [&](size_t bytes) {
        char* p = ws + off;
        off += (bytes + 255) & ~(size_t)255;
        return p;
    };
    float* dinv    = (float*)alloc((size_t)N * 4);
    int*   row_off = (int*)  alloc((size_t)(N + 1) * 4);
    int*   bcnt    = (int*)  alloc((size_t)(NB + 1) * 4);
    int*   boff    = (int*)  alloc((size_t)(NB + 1) * 4);
    int*   bcur    = (int*)  alloc((size_t)NB * 4);
    int*   esrc    = (int*)  alloc((size_t)E * 4);
    size_t shsz    = (size_t)E * 4 > (size_t)N * 128 ? (size_t)E * 4 : (size_t)N * 128;
    char*  shared_region = alloc(shsz);            // pairs u32 (12.8MB) / G1 (12.8MB)
    uint*  pairs   = (uint*)shared_region;
    ushort* G1     = (ushort*)shared_region;       // [4][N][16]
    ushort* G2     = (ushort*)alloc((size_t)N * 32 * 2);   // [2][N][16]
    ushort* G3     = (ushort*)alloc((size_t)N * 16 * 2);   // [1][N][16]
    float* Xb      = (float*)alloc((size_t)N * 64 * 4);
    ushort* Wh1 = (ushort*)alloc(16384 * 2), *Wl1 = (ushort*)alloc(16384 * 2);
    ushort* Wh2 = (ushort*)alloc(2048 * 2),  *Wl2 = (ushort*)alloc(2048 * 2);
    ushort* Wh3 = (ushort*)alloc(512 * 2),   *Wl3 = (ushort*)alloc(512 * 2);
    float* out     = (float*)d_out;

    // --- CSR build + dinv + W prep ---
    constexpr int CH = 4096;
    constexpr int HB = 1024;              // histogram blocks in k_pre
    const int nch = (E + CH - 1) / CH;
    hipMemsetAsync(bcnt, 0, (size_t)NB * 4, stream);
    hipLaunchKernelGGL(k_pre, dim3(HB + 74), dim3(256), 0, stream,
                       dstv, bcnt, E, HB,
                       W1, W2, W3, Wh1, Wl1, Wh2, Wl2, Wh3, Wl3);
    hipLaunchKernelGGL(k_bscan,  dim3(1), dim3(1024), 0, stream, bcnt, boff, bcur, NB);
    hipLaunchKernelGGL((k_part<CH>), dim3(nch), dim3(256), 0, stream,
                       src, dstv, bcur, pairs, E, NB);
    hipLaunchKernelGGL(k_bucket, dim3(NB), dim3(1024), 0, stream,
                       pairs, boff, row_off, dinv, esrc, N, NB, E);

    const int gb = (N + 63) / 64;
    const int ab = (N + 3) / 4;   // 4 waves / block

    // --- layer 1: 256 -> 64 ---  (G1 overwrites pairs; dead after k_bucket)
    hipLaunchKernelGGL((k_mfma<256, 64>), dim3(gb), dim3(256), 0, stream,
                       emb, 256, nodes, Wh1, Wl1, dinv, G1, N);
    for (int sl = 0; sl < 4; ++sl)
        hipLaunchKernelGGL((k_aggs<64>), dim3(ab), dim3(256), 0, stream,
                           row_off, esrc,
                           (const uint2*)(G1 + (size_t)sl * N * 16),
                           dinv, b1 + sl * 16, Xb + sl * 16, N);
    // --- layer 2: 64 -> 32 ---
    hipLaunchKernelGGL((k_mfma<64, 32>), dim3(gb), dim3(256), 0, stream,
                       Xb, 64, (const int*)nullptr, Wh2, Wl2, dinv, G2, N);
    for (int sl = 0; sl < 2; ++sl)
        hipLaunchKernelGGL((k_aggs<64>), dim3(ab), dim3(256), 0, stream,
                           row_off, esrc,
                           (const uint2*)(G2 + (size_t)sl * N * 16),
                           dinv, b2 + sl * 16, Xb + sl * 16, N);
    // --- layer 3: 32 -> 16 ---
    hipLaunchKernelGGL((k_mfma<32, 16>), dim3(gb), dim3(256), 0, stream,
                       Xb, 64, (const int*)nullptr, Wh3, Wl3, dinv, G3, N);
    hipLaunchKernelGGL((k_aggs<16>), dim3(ab), dim3(256), 0, stream,
                       row_off, esrc, (const uint2*)G3, dinv, b3, out, N);
}

// Round 10
// 306.235 us; speedup vs baseline: 1.3359x; 1.3359x over previous
//
#include <hip/hip_runtime.h>

// ---------------------------------------------------------------------------
// 3-layer GCN forward. out[d] = relu( dinv[d]*( sum_{s->d} g[s] + g[d] ) + b ),
// g = (x@W)*dinv stored bf16 row-major [N][OF] (halves gather traffic).
// GEMMs: split-bf16 MFMA (x = hi+lo, 3 passes => ~f32 accuracy) with
// register-prefetch pipelining of the A (X) staging loads (r9: 1.6TB/s, 5.7%
// MfmaUtil => barrier-fenced loads were the limiter).
// CSR: two-level counting sort; k_part now LDS-reorders each 8192-edge chunk
// into bucket-major order before writing => coalesced runs, no 4x write
// amplification (r9: 51MB written for 12.8MB payload).
// r9 slice experiment reverted (esrc re-stream + partial-row Xb writes).
// ---------------------------------------------------------------------------

#define BSH 9                 // 512 nodes per bucket
#define BNODES (1 << BSH)

typedef __attribute__((ext_vector_type(8))) short bf16x8;
typedef __attribute__((ext_vector_type(4))) float f32x4;

__device__ inline ushort f2bf(float x) {   // round-to-nearest-even f32->bf16
    uint u = __float_as_uint(x);
    return (ushort)((u + 0x7fffu + ((u >> 16) & 1u)) >> 16);
}
__device__ inline float bf2f(ushort h) { return __uint_as_float(((uint)h) << 16); }
__device__ inline void split2(float x, ushort& h, ushort& l) {
    ushort hh = f2bf(x);
    h = hh;
    l = f2bf(x - bf2f(hh));
}

// fused: bucket histogram of dst (blocks < HB) + W1/W2/W3 split/transpose
__global__ __launch_bounds__(256) void k_pre(
    const int* __restrict__ dst, int* __restrict__ bcnt, int E, int HB,
    const float* __restrict__ W1, const float* __restrict__ W2,
    const float* __restrict__ W3,
    ushort* __restrict__ Wh1, ushort* __restrict__ Wl1,
    ushort* __restrict__ Wh2, ushort* __restrict__ Wl2,
    ushort* __restrict__ Wh3, ushort* __restrict__ Wl3)
{
    if ((int)blockIdx.x < HB) {
        __shared__ int h[256];
        int t = threadIdx.x;
        h[t] = 0;
        __syncthreads();
        for (int i = blockIdx.x * 256 + t; i < E; i += HB * 256)
            atomicAdd(&h[dst[i] >> BSH], 1);
        __syncthreads();
        if (h[t]) atomicAdd(&bcnt[t], h[t]);
        return;
    }
    int i = (blockIdx.x - HB) * 256 + threadIdx.x;
    ushort h, l;
    if (i < 16384) {                       // W1: 256x64
        int k = i >> 6, n = i & 63;
        split2(W1[i], h, l);
        Wh1[n * 256 + k] = h; Wl1[n * 256 + k] = l;
    } else if (i < 16384 + 2048) {         // W2: 64x32
        int j = i - 16384;
        int k = j >> 5, n = j & 31;
        split2(W2[j], h, l);
        Wh2[n * 64 + k] = h; Wl2[n * 64 + k] = l;
    } else if (i < 16384 + 2048 + 512) {   // W3: 32x16
        int j = i - 18432;
        int k = j >> 4, n = j & 15;
        split2(W3[j], h, l);
        Wh3[n * 32 + k] = h; Wl3[n * 32 + k] = l;
    }
}

// scan bucket counts -> boff (exclusive), init bcur. NB <= 1024.
__global__ __launch_bounds__(1024) void k_bscan(const int* __restrict__ bcnt,
                                                int* __restrict__ boff,
                                                int* __restrict__ bcur, int NB) {
    __shared__ int s[1024];
    int t = threadIdx.x;
    int v = (t < NB) ? bcnt[t] : 0;
    s[t] = v;
    __syncthreads();
    for (int off = 1; off < 1024; off <<= 1) {
        int a = (t >= off) ? s[t - off] : 0;
        __syncthreads();
        s[t] += a;
        __syncthreads();
    }
    if (t < NB) {
        int ex = s[t] - v;
        boff[t] = ex;
        bcur[t] = ex;
    }
    if (t == NB - 1) boff[NB] = s[t];
}

// partition edges into bucket-contiguous packed (local_dst<<23 | src) words.
// v2: LDS reorder — bin the chunk bucket-major in LDS, then write coalesced
// runs (avg ~170B) instead of interleaved 4B scatter (r9: 4x write amp).
template <int CH>
__global__ __launch_bounds__(256) void k_part(const int* __restrict__ src,
                                              const int* __restrict__ dst,
                                              int* __restrict__ bcur,
                                              uint* __restrict__ pairs,
                                              int E, int NB) {
    __shared__ uint sval[CH];
    __shared__ unsigned char sbid[CH];     // NB <= 256
    __shared__ int lh[256], lofs[256], lbase[256], cur[256];
    const int t = threadIdx.x;
    const int e0 = blockIdx.x * CH;
    const int n = min(CH, E - e0);

    lh[t] = 0;
    cur[t] = 0;
    __syncthreads();
    for (int i = t; i < n; i += 256) atomicAdd(&lh[dst[e0 + i] >> BSH], 1);
    __syncthreads();
    int v = lh[t];
    lofs[t] = v;
    __syncthreads();
    for (int off = 1; off < 256; off <<= 1) {
        int a = (t >= off) ? lofs[t - off] : 0;
        __syncthreads();
        lofs[t] += a;
        __syncthreads();
    }
    int ex = lofs[t] - v;                  // exclusive scan value
    if (v > 0) lbase[t] = atomicAdd(&bcur[t], v);
    __syncthreads();
    lofs[t] = ex;
    __syncthreads();
    for (int i = t; i < n; i += 256) {
        int d = dst[e0 + i];
        int b = d >> BSH;
        int r = atomicAdd(&cur[b], 1);
        int slot = lofs[b] + r;
        sval[slot] = ((uint)(d & (BNODES - 1)) << 23) | (uint)src[e0 + i];
        sbid[slot] = (unsigned char)b;
    }
    __syncthreads();
    for (int i = t; i < n; i += 256) {
        int b = sbid[i];
        pairs[(long)lbase[b] + (i - lofs[b])] = sval[i];
    }
}

// per-bucket: per-node histogram + scan (LDS), emit row_off/dinv, scatter esrc
__global__ __launch_bounds__(1024) void k_bucket(const uint* __restrict__ pairs,
                                                 const int* __restrict__ boff,
                                                 int* __restrict__ row_off,
                                                 float* __restrict__ dinv,
                                                 int* __restrict__ esrc,
                                                 int N, int NB, int E) {
    __shared__ int cnt[BNODES];
    __shared__ int sc[BNODES];
    __shared__ int cur[BNODES];
    const int b = blockIdx.x;
    const int t = threadIdx.x;
    const int base = b << BSH;
    const int nn = min(BNODES, N - base);
    const int ebase = boff[b], eend = boff[b + 1];

    if (t < BNODES) cnt[t] = 0;
    __syncthreads();
    for (int e = ebase + t; e < eend; e += 1024)
        atomicAdd(&cnt[pairs[e] >> 23], 1);
    __syncthreads();
    if (t < BNODES) sc[t] = cnt[t];
    __syncthreads();
    for (int off = 1; off < BNODES; off <<= 1) {
        int a = (t < BNODES && t >= off) ? sc[t - off] : 0;
        __syncthreads();
        if (t < BNODES) sc[t] += a;
        __syncthreads();
    }
    if (t < nn) {
        int ex = sc[t] - cnt[t];
        row_off[base + t] = ebase + ex;
        cur[t] = ex;
        dinv[base + t] = rsqrtf((float)(cnt[t] + 1));
    }
    if (b == NB - 1 && t == 0) row_off[N] = E;
    __syncthreads();
    for (int e = ebase + t; e < eend; e += 1024) {
        uint p = pairs[e];
        int r = atomicAdd(&cur[p >> 23], 1);
        esrc[ebase + r] = (int)(p & 0x7fffffu);
    }
}

// ---------------------------------------------------------------------------
// Split-bf16 MFMA GEMM: G[n][0..OF) = bf16( (X[row(n)] @ W) * dinv[n] ),
// row-major stride OF. Block = 64 rows x OF cols, 4 waves, BK=32 per step.
// A-staging loads register-prefetched one K-step ahead (hides HBM latency
// under B-staging + frag reads + MFMA).
// ---------------------------------------------------------------------------
template <int K, int OF>
__global__ __launch_bounds__(256) void k_mfma(
    const float* __restrict__ X, int sx,
    const int* __restrict__ nodes,          // may be null (identity)
    const ushort* __restrict__ Wh,          // [OF][K] bf16
    const ushort* __restrict__ Wl,
    const float* __restrict__ dinv,
    ushort* __restrict__ G,                 // bf16, packed stride OF
    int N)
{
    constexpr int BM = 64, BK = 32, LDF = 40;
    constexpr int NT = OF / 16;             // MFMA col tiles
    __shared__ ushort Ah[BM * LDF], Al[BM * LDF];
    __shared__ ushort Bh[OF * LDF], Bl[OF * LDF];

    const int tid = threadIdx.x;
    const int l = tid & 63;
    const int w = tid >> 6;                 // wave id: rows w*16..w*16+15
    const int m0 = blockIdx.x * BM;
    const int lm = l & 15, kg = l >> 4;
    const int ma = tid >> 3, kqa = tid & 7; // staging coords: rows ma, ma+32

    // row pointers for the two staged rows (loop-invariant)
    const float* xr0 = nullptr;
    const float* xr1 = nullptr;
    if (m0 + ma < N) {
        long r = nodes ? (long)nodes[m0 + ma] : (long)(m0 + ma);
        xr0 = X + r * (long)sx + kqa * 4;
    }
    if (m0 + ma + 32 < N) {
        long r = nodes ? (long)nodes[m0 + ma + 32] : (long)(m0 + ma + 32);
        xr1 = X + r * (long)sx + kqa * 4;
    }

    f32x4 acc[NT];
#pragma unroll
    for (int nt = 0; nt < NT; ++nt) acc[nt] = (f32x4){0.f, 0.f, 0.f, 0.f};

    float4 v0 = make_float4(0.f, 0.f, 0.f, 0.f);
    float4 v1 = make_float4(0.f, 0.f, 0.f, 0.f);
    if (xr0) v0 = *reinterpret_cast<const float4*>(xr0);
    if (xr1) v1 = *reinterpret_cast<const float4*>(xr1);

    for (int k0 = 0; k0 < K; k0 += BK) {
        __syncthreads();
        // write current A chunk (f32 -> hi/lo bf16)
        {
            ushort4 hh, ll;
            split2(v0.x, hh.x, ll.x); split2(v0.y, hh.y, ll.y);
            split2(v0.z, hh.z, ll.z); split2(v0.w, hh.w, ll.w);
            *reinterpret_cast<ushort4*>(&Ah[ma * LDF + kqa * 4]) = hh;
            *reinterpret_cast<ushort4*>(&Al[ma * LDF + kqa * 4]) = ll;
            split2(v1.x, hh.x, ll.x); split2(v1.y, hh.y, ll.y);
            split2(v1.z, hh.z, ll.z); split2(v1.w, hh.w, ll.w);
            *reinterpret_cast<ushort4*>(&Ah[(ma + 32) * LDF + kqa * 4]) = hh;
            *reinterpret_cast<ushort4*>(&Al[(ma + 32) * LDF + kqa * 4]) = ll;
        }
        // prefetch next A chunk (in flight across the MFMA phase)
        if (k0 + BK < K) {
            v0 = make_float4(0.f, 0.f, 0.f, 0.f);
            v1 = make_float4(0.f, 0.f, 0.f, 0.f);
            if (xr0) v0 = *reinterpret_cast<const float4*>(xr0 + k0 + BK);
            if (xr1) v1 = *reinterpret_cast<const float4*>(xr1 + k0 + BK);
        }
        // stage B (small, L2-hot)
        for (int i = tid; i < OF * 16; i += 256) {
            int n = i >> 4, ku = i & 15;
            *reinterpret_cast<uint*>(&Bh[n * LDF + ku * 2]) =
                *reinterpret_cast<const uint*>(Wh + (long)n * K + k0 + ku * 2);
            *reinterpret_cast<uint*>(&Bl[n * LDF + ku * 2]) =
                *reinterpret_cast<const uint*>(Wl + (long)n * K + k0 + ku * 2);
        }
        __syncthreads();

        bf16x8 ah = *reinterpret_cast<bf16x8*>(&Ah[(w * 16 + lm) * LDF + kg * 8]);
        bf16x8 al = *reinterpret_cast<bf16x8*>(&Al[(w * 16 + lm) * LDF + kg * 8]);
#pragma unroll
        for (int nt = 0; nt < NT; ++nt) {
            bf16x8 bh = *reinterpret_cast<bf16x8*>(&Bh[(nt * 16 + lm) * LDF + kg * 8]);
            bf16x8 bl = *reinterpret_cast<bf16x8*>(&Bl[(nt * 16 + lm) * LDF + kg * 8]);
            acc[nt] = __builtin_amdgcn_mfma_f32_16x16x32_bf16(al, bh, acc[nt], 0, 0, 0);
            acc[nt] = __builtin_amdgcn_mfma_f32_16x16x32_bf16(ah, bl, acc[nt], 0, 0, 0);
            acc[nt] = __builtin_amdgcn_mfma_f32_16x16x32_bf16(ah, bh, acc[nt], 0, 0, 0);
        }
    }
#pragma unroll
    for (int r = 0; r < 4; ++r) {
        int m = m0 + w * 16 + kg * 4 + r;
        if (m < N) {
            float dv = dinv[m];
#pragma unroll
            for (int nt = 0; nt < NT; ++nt)
                G[(long)m * OF + nt * 16 + lm] = f2bf(acc[nt][r] * dv);
        }
    }
}

// ---------------------------------------------------------------------------
// CSR aggregation (bf16 uint2 gather, f32 accum) + self-loop + epilogue.
// One wave per node; OF/4 lanes per edge; 8 gathers in flight (2x4 groups),
// 4 accumulator sets. Plain cached loads (r6: nontemporal hurt).
// ---------------------------------------------------------------------------
#define UNPK(AC, W)                                                 \
    AC.x += __uint_as_float((W).x << 16);                           \
    AC.y += __uint_as_float((W).x & 0xffff0000u);                   \
    AC.z += __uint_as_float((W).y << 16);                           \
    AC.w += __uint_as_float((W).y & 0xffff0000u);

template <int OF, int OSTRIDE>
__global__ __launch_bounds__(256) void k_agg(
    const int* __restrict__ row_off, const int* __restrict__ esrc,
    const uint2* __restrict__ g,     // row = OF/2 bf16x2 words
    const float* __restrict__ dinv, const float* __restrict__ b,
    float* __restrict__ y, int N)
{
    constexpr int WPE = OF / 4;      // lanes per edge
    constexpr int EPW = 64 / WPE;    // edges in parallel
    const int lane = threadIdx.x & 63;
    const int q = lane % WPE;        // feature quad
    const int sub = lane / WPE;
    const int n = blockIdx.x * (blockDim.x >> 6) + (threadIdx.x >> 6);
    if (n >= N) return;
    const int start = row_off[n], end = row_off[n + 1];

    float4 ac[4];
#pragma unroll
    for (int u = 0; u < 4; ++u) ac[u] = make_float4(0.f, 0.f, 0.f, 0.f);

    int e = start + sub;
    for (; e + 7 * EPW < end; e += 8 * EPW) {
        int s0[4], s1[4];
#pragma unroll
        for (int u = 0; u < 4; ++u) s0[u] = esrc[e + u * EPW];
#pragma unroll
        for (int u = 0; u < 4; ++u) s1[u] = esrc[e + (4 + u) * EPW];
        uint2 w0[4], w1[4];
#pragma unroll
        for (int u = 0; u < 4; ++u) w0[u] = g[(long)s0[u] * WPE + q];
#pragma unroll
        for (int u = 0; u < 4; ++u) w1[u] = g[(long)s1[u] * WPE + q];
#pragma unroll
        for (int u = 0; u < 4; ++u) { UNPK(ac[u], w0[u]); }
#pragma unroll
        for (int u = 0; u < 4; ++u) { UNPK(ac[u], w1[u]); }
    }
    for (; e + 3 * EPW < end; e += 4 * EPW) {
        int s[4];
        uint2 w[4];
#pragma unroll
        for (int u = 0; u < 4; ++u) s[u] = esrc[e + u * EPW];
#pragma unroll
        for (int u = 0; u < 4; ++u) w[u] = g[(long)s[u] * WPE + q];
#pragma unroll
        for (int u = 0; u < 4; ++u) { UNPK(ac[u], w[u]); }
    }
    for (; e < end; e += EPW) {
        uint2 w = g[(long)esrc[e] * WPE + q];
        UNPK(ac[0], w);
    }
    float4 a;
    a.x = (ac[0].x + ac[1].x) + (ac[2].x + ac[3].x);
    a.y = (ac[0].y + ac[1].y) + (ac[2].y + ac[3].y);
    a.z = (ac[0].z + ac[1].z) + (ac[2].z + ac[3].z);
    a.w = (ac[0].w + ac[1].w) + (ac[2].w + ac[3].w);
#pragma unroll
    for (int m = WPE; m < 64; m <<= 1) {
        a.x += __shfl_xor(a.x, m, 64);
        a.y += __shfl_xor(a.y, m, 64);
        a.z += __shfl_xor(a.z, m, 64);
        a.w += __shfl_xor(a.w, m, 64);
    }
    if (sub == 0) {
        uint2 sv = g[(long)n * WPE + q];   // self loop
        a.x += __uint_as_float(sv.x << 16); a.y += __uint_as_float(sv.x & 0xffff0000u);
        a.z += __uint_as_float(sv.y << 16); a.w += __uint_as_float(sv.y & 0xffff0000u);
        float dv = dinv[n];
        float4 bb = *reinterpret_cast<const float4*>(&b[q * 4]);
        float4 o;
        o.x = fmaxf(fmaf(a.x, dv, bb.x), 0.f);
        o.y = fmaxf(fmaf(a.y, dv, bb.y), 0.f);
        o.z = fmaxf(fmaf(a.z, dv, bb.z), 0.f);
        o.w = fmaxf(fmaf(a.w, dv, bb.w), 0.f);
        *reinterpret_cast<float4*>(&y[(long)n * OSTRIDE + q * 4]) = o;
    }
}

extern "C" void kernel_launch(void* const* d_in, const int* in_sizes, int n_in,
                              void* d_out, int out_size, void* d_ws, size_t ws_size,
                              hipStream_t stream) {
    const int*   nodes = (const int*)d_in[0];
    const int*   edges = (const int*)d_in[1];
    const float* emb   = (const float*)d_in[2];
    const float* W1    = (const float*)d_in[3];
    const float* b1    = (const float*)d_in[4];
    const float* W2    = (const float*)d_in[5];
    const float* b2    = (const float*)d_in[6];
    const float* W3    = (const float*)d_in[7];
    const float* b3    = (const float*)d_in[8];

    const int N = in_sizes[0];
    const int E = in_sizes[1] / 2;
    const int* src  = edges;
    const int* dstv = edges + E;
    const int NB = (N + BNODES - 1) >> BSH;   // 196 for N=100000

    char* ws = (char*)d_ws;
    size_t off = 0;
    auto alloc = [&](size_t bytes) {
        char* p = ws + off;
        off += (bytes + 255) & ~(size_t)255;
        return p;
    };
    float* dinv    = (float*)alloc((size_t)N * 4);
    int*   row_off = (int*)  alloc((size_t)(N + 1) * 4);
    int*   bcnt    = (int*)  alloc((size_t)(NB + 1) * 4);
    int*   boff    = (int*)  alloc((size_t)(NB + 1) * 4);
    int*   bcur    = (int*)  alloc((size_t)NB * 4);
    int*   esrc    = (int*)  alloc((size_t)E * 4);
    size_t shsz    = (size_t)E * 4 > (size_t)N * 128 ? (size_t)E * 4 : (size_t)N * 128;
    char*  shared_region = alloc(shsz);            // pairs u32 (12.8MB) / G1 (12.8MB)
    uint*  pairs   = (uint*)shared_region;
    ushort* G1     = (ushort*)shared_region;       // [N][64] bf16
    ushort* G2     = (ushort*)alloc((size_t)N * 32 * 2);
    ushort* G3     = (ushort*)alloc((size_t)N * 16 * 2);
    float* Xb      = (float*)alloc((size_t)N * 64 * 4);
    ushort* Wh1 = (ushort*)alloc(16384 * 2), *Wl1 = (ushort*)alloc(16384 * 2);
    ushort* Wh2 = (ushort*)alloc(2048 * 2),  *Wl2 = (ushort*)alloc(2048 * 2);
    ushort* Wh3 = (ushort*)alloc(512 * 2),   *Wl3 = (ushort*)alloc(512 * 2);
    float* out     = (float*)d_out;

    // --- CSR build + dinv + W prep ---
    constexpr int CH = 8192;
    constexpr int HB = 1024;              // histogram blocks in k_pre
    const int nch = (E + CH - 1) / CH;
    hipMemsetAsync(bcnt, 0, (size_t)NB * 4, stream);
    hipLaunchKernelGGL(k_pre, dim3(HB + 74), dim3(256), 0, stream,
                       dstv, bcnt, E, HB,
                       W1, W2, W3, Wh1, Wl1, Wh2, Wl2, Wh3, Wl3);
    hipLaunchKernelGGL(k_bscan,  dim3(1), dim3(1024), 0, stream, bcnt, boff, bcur, NB);
    hipLaunchKernelGGL((k_part<CH>), dim3(nch), dim3(256), 0, stream,
                       src, dstv, bcur, pairs, E, NB);
    hipLaunchKernelGGL(k_bucket, dim3(NB), dim3(1024), 0, stream,
                       pairs, boff, row_off, dinv, esrc, N, NB, E);

    const int gb = (N + 63) / 64;
    const int ab = (N + 3) / 4;   // 4 waves / block

    // --- layer 1: 256 -> 64 ---  (G1 overwrites pairs; dead after k_bucket)
    hipLaunchKernelGGL((k_mfma<256, 64>), dim3(gb), dim3(256), 0, stream,
                       emb, 256, nodes, Wh1, Wl1, dinv, G1, N);
    hipLaunchKernelGGL((k_agg<64, 64>), dim3(ab), dim3(256), 0, stream,
                       row_off, esrc, (const uint2*)G1, dinv, b1, Xb, N);
    // --- layer 2: 64 -> 32 ---
    hipLaunchKernelGGL((k_mfma<64, 32>), dim3(gb), dim3(256), 0, stream,
                       Xb, 64, (const int*)nullptr, Wh2, Wl2, dinv, G2, N);
    hipLaunchKernelGGL((k_agg<32, 64>), dim3(ab), dim3(256), 0, stream,
                       row_off, esrc, (const uint2*)G2, dinv, b2, Xb, N);
    // --- layer 3: 32 -> 16 ---
    hipLaunchKernelGGL((k_mfma<32, 16>), dim3(gb), dim3(256), 0, stream,
                       Xb, 64, (const int*)nullptr, Wh3, Wl3, dinv, G3, N);
    hipLaunchKernelGGL((k_agg<16, 16>), dim3(ab), dim3(256), 0, stream,
                       row_off, esrc, (const uint2*)G3, dinv, b3, out, N);
}